// Round 10
// baseline (128.658 us; speedup 1.0000x reference)
//
#include <hip/hip_runtime.h>

// ---------------- problem constants ----------------
#define NB    1024
#define NN    19
#define NF    8
#define CCH   152         // NN*NF
#define TLEN  512
#define TP    128
#define GO    16
#define KFLAT 38912       // reference flat K (n*2048 + t*16 + o)
#define HID   128
#define NCLS  2
#define NROWS (NB*TP)     // 131072 (b,t) rows
#define KC    152         // conv channels (j,f)
#define KP    160         // padded K for mix (5*32)
#define NJP   20          // H j-planes (19 + zero pad)
#define NOUT  304         // NN*GO
#define GW    320         // g2 padded row width
#define KW    (TP*GW)     // 40960: FC1 K in permuted order
#define XROW  520         // xs row stride (floats); used [0,517)

// FC1 GEMM split-K
#define KTILE 1024
#define NKT   (KW / KTILE)   // 40

typedef float  f32x4  __attribute__((ext_vector_type(4)));
typedef __bf16 bf16x8 __attribute__((ext_vector_type(8)));
typedef __bf16 bf16x4 __attribute__((ext_vector_type(4)));
typedef unsigned short u16x8 __attribute__((ext_vector_type(8)));

// ---------------------------------------------------------------------------
// P1: softmax(adj) + fused BN affine (1 block)
// ---------------------------------------------------------------------------
__global__ __launch_bounds__(256) void prep_small(
    const float* __restrict__ adj,
    const float* __restrict__ bn_gamma, const float* __restrict__ bn_beta,
    const float* __restrict__ bn_mean,  const float* __restrict__ bn_var,
    const float* __restrict__ conv_b,
    float* __restrict__ A_g, float* __restrict__ bnS, float* __restrict__ bnB)
{
    const int tid = threadIdx.x;
    if (tid < NN) {
        float v[NN];
        float m = -1e30f;
        #pragma unroll
        for (int j = 0; j < NN; ++j) { v[j] = adj[tid * NN + j]; m = fmaxf(m, v[j]); }
        float s = 0.f;
        #pragma unroll
        for (int j = 0; j < NN; ++j) { v[j] = expf(v[j] - m); s += v[j]; }
        float rc = 1.f / s;
        #pragma unroll
        for (int j = 0; j < NN; ++j) A_g[tid * NN + j] = v[j] * rc;
    }
    if (tid >= 64 && tid < 64 + CCH) {
        int c = tid - 64;
        float inv = bn_gamma[c] * rsqrtf(bn_var[c] + 1e-5f);
        bnS[c] = inv;
        bnB[c] = conv_b[c] * inv + bn_beta[c] - bn_mean[c] * inv;
    }
}

// ---------------------------------------------------------------------------
// P2: Kronecker matrix m2g[c][k] = A[n,j]*gcn_w[o,f], c=(n*16+o) in [0,320)
// ---------------------------------------------------------------------------
__global__ __launch_bounds__(256) void prep_m2(
    const float* __restrict__ A_g, const float* __restrict__ gcn_w,
    __bf16* __restrict__ m2g)
{
    int i = blockIdx.x * 256 + threadIdx.x;
    if (i >= GW * KP) return;
    int c = i / KP, k = i - c * KP;
    float v = 0.f;
    if (c < NOUT && k < KC) {
        int n = c >> 4, o = c & 15;
        int j = k >> 3, f = k & 7;
        v = A_g[n * NN + j] * gcn_w[o * NF + f];
    }
    m2g[i] = (__bf16)v;
}

// ---------------------------------------------------------------------------
// F: FUSED conv(k5 depthwise)+bias+BN+ReLU+maxpool4 + A-mix/gcn MFMA
//    -> g2[(b,t)][320]. One block per batch b; H lives only in LDS
//    (kills the 42 MB write + 42 MB read round-trip of R9's two kernels).
//    Phase 1 conv: n is wave-uniform (n = (w>>1) + 2k) -> scalar weight loads.
//    Phase 2 mix: R8/R9's proven reg-resident-m2 loop, H frags from LDS.
// ---------------------------------------------------------------------------
__global__ __launch_bounds__(256) void conv_mix(
    const float* __restrict__ x,       // [NB][NN][TLEN]
    const float* __restrict__ conv_w,  // [CCH][5]
    const float* __restrict__ bnS, const float* __restrict__ bnB,
    const __bf16* __restrict__ m2g,    // [GW][KP]
    const float* __restrict__ gcn_b,   // [GO]
    __bf16* __restrict__ g2)           // [NROWS][GW]
{
    __shared__ __align__(16) float  xs[NN][XROW];       // 39,520 B
    __shared__ __align__(16) __bf16 Hs[NJP][TP][8];     // 40,960 B

    const int tid  = threadIdx.x;
    const int lane = tid & 63, w = tid >> 6;
    const int b    = blockIdx.x;

    // ---- phase 0: stage x[b] with halo (tl = tg+2, need tl in [0,517)) ----
    const float* xb = x + (size_t)b * (NN * TLEN);
    for (unsigned i = tid; i < NN * 517u; i += 256) {
        unsigned n = i / 517u, tl = i - n * 517u;
        int tg = (int)tl - 2;
        xs[n][tl] = (tg >= 0 && tg < TLEN) ? xb[n * TLEN + tg] : 0.f;
    }
    __syncthreads();

    // ---- phase 1: conv+bn+relu+pool -> Hs[n][t][f], n wave-uniform ----
    {
        const int t = lane + (w & 1) * 64;     // 0..127
        const int n0 = w >> 1;                 // 0 or 1
        for (int k = 0; ; ++k) {
            const int n = n0 + 2 * k;
            if (n >= NN) break;
            const float* cw = conv_w + n * (NF * 5);
            const float* Sp = bnS + n * NF;
            const float* Bp = bnB + n * NF;
            const float* xr = &xs[n][4 * t];
            float xv[9];
            #pragma unroll
            for (int e = 0; e < 9; ++e) xv[e] = xr[e];
            union { __bf16 h[8]; u16x8 v; } hv;
            #pragma unroll
            for (int f = 0; f < NF; ++f) {
                float w0 = cw[f*5+0], w1 = cw[f*5+1], w2 = cw[f*5+2], w3 = cw[f*5+3], w4 = cw[f*5+4];
                float s = Sp[f], bb = Bp[f];
                float m = -1e30f;
                #pragma unroll
                for (int p = 0; p < 4; ++p) {
                    float a = xv[p]*w0 + xv[p+1]*w1 + xv[p+2]*w2 + xv[p+3]*w3 + xv[p+4]*w4;
                    m = fmaxf(m, a * s + bb);
                }
                hv.h[f] = (__bf16)fmaxf(m, 0.f);
            }
            *(u16x8*)&Hs[n][t][0] = hv.v;
        }
        if (w == 3) {                          // zero plane 19 (K pad)
            u16x8 z = {0,0,0,0,0,0,0,0};
            *(u16x8*)&Hs[NJP - 1][(w & 1) * 64 + lane][0] = z;
            *(u16x8*)&Hs[NJP - 1][lane][0] = z;
        }
    }

    // ---- m2 fragments from L2 (independent of LDS; latency hides in barrier) ----
    const int arow = lane & 15;
    const int jg   = lane >> 4;            // 0..3
    const int ct0  = w * 5;                // wave's 5 ct-tiles (80 cols)
    const float4 gbv = *(const float4*)(gcn_b + jg * 4);

    bf16x8 mf[5][5];
    #pragma unroll
    for (int ct = 0; ct < 5; ++ct)
        #pragma unroll
        for (int ks = 0; ks < 5; ++ks)
            mf[ct][ks] = *(const bf16x8*)(
                m2g + (size_t)((ct0 + ct) * 16 + arow) * KP + ks * 32 + jg * 8);

    __syncthreads();

    // ---- phase 2: 8 row-tiles x 25 MFMA, H frags from LDS ----
    for (int it = 0; it < 8; ++it) {
        const int t16 = it * 16 + arow;

        bf16x8 af[5];
        #pragma unroll
        for (int ks = 0; ks < 5; ++ks)
            af[ks] = *(const bf16x8*)&Hs[ks * 4 + jg][t16][0];

        f32x4 acc[5];
        #pragma unroll
        for (int ct = 0; ct < 5; ++ct) acc[ct] = (f32x4){0.f, 0.f, 0.f, 0.f};

        #pragma unroll
        for (int ks = 0; ks < 5; ++ks)
            #pragma unroll
            for (int ct = 0; ct < 5; ++ct)
                acc[ct] = __builtin_amdgcn_mfma_f32_16x16x32_bf16(mf[ct][ks], af[ks], acc[ct], 0, 0, 0);

        // C^T: lane holds cols c = (ct0+ct)*16 + jg*4 + r for g2 row b*128+t16
        __bf16* gp = g2 + ((size_t)b * TP + t16) * GW + ct0 * 16 + jg * 4;
        #pragma unroll
        for (int ct = 0; ct < 5; ++ct) {
            bf16x4 v;
            v[0] = (__bf16)fmaxf(acc[ct][0] + gbv.x, 0.f);
            v[1] = (__bf16)fmaxf(acc[ct][1] + gbv.y, 0.f);
            v[2] = (__bf16)fmaxf(acc[ct][2] + gbv.z, 0.f);
            v[3] = (__bf16)fmaxf(acc[ct][3] + gbv.w, 0.f);
            *(bf16x4*)(gp + ct * 16) = v;
        }
    }
}

// ---------------------------------------------------------------------------
// W: permute+convert w1 -> w1p[j][t*320 + c] bf16 (c=(n*16+o); pad cols 0)
// ---------------------------------------------------------------------------
__global__ __launch_bounds__(256) void w1_permute(
    const float* __restrict__ w1, __bf16* __restrict__ w1p)
{
    int i = blockIdx.x * 256 + threadIdx.x;    // chunk: j*5120 + t*40 + c8
    if (i >= HID * (KW / 8)) return;
    int j = i / 5120, rem = i - j * 5120;
    int t = rem / 40, c8 = rem - t * 40;
    bf16x8 r;
    if (c8 < 38) {
        int n = c8 >> 1, o0 = (c8 & 1) * 8;
        const float* src = w1 + (size_t)j * KFLAT + n * 2048 + t * 16 + o0;
        #pragma unroll
        for (int e = 0; e < 8; ++e) r[e] = (__bf16)src[e];
    } else {
        #pragma unroll
        for (int e = 0; e < 8; ++e) r[e] = (__bf16)0.f;
    }
    *(bf16x8*)(w1p + (size_t)i * 8) = r;
}

// ---------------------------------------------------------------------------
// G: split-K bf16 MFMA GEMM: partial[kt][b][j] = sum_k g2[b][k]*w1p[j][k]
// ---------------------------------------------------------------------------
__global__ __launch_bounds__(256) void gemm_fc1(
    const __bf16* __restrict__ gmat,   // [NB][KW]
    const __bf16* __restrict__ wmat,   // [HID][KW]
    float* __restrict__ partial)       // [NKT][NB][HID]
{
    __shared__ __align__(16) __bf16 At[128][40];
    __shared__ __align__(16) __bf16 Bt[128][40];

    const int tid = threadIdx.x;
    const int b0 = blockIdx.x * 128;
    const int k0 = blockIdx.y * KTILE;

    const int lane = tid & 63;
    const int w = tid >> 6;
    const int wm = (w >> 1) * 64;
    const int wn = (w & 1) * 64;

    const int srow = tid >> 2;
    const int soct = tid & 3;

    f32x4 acc[4][4];
    #pragma unroll
    for (int m = 0; m < 4; ++m)
        #pragma unroll
        for (int n = 0; n < 4; ++n) acc[m][n] = (f32x4){0.f, 0.f, 0.f, 0.f};

    const int arow = lane & 15;
    const int aoct = (lane >> 4) * 8;

    for (int ks = 0; ks < KTILE / 32; ++ks) {
        const int gk = k0 + ks * 32 + soct * 8;
        *(u16x8*)&At[srow     ][soct * 8] = *(const u16x8*)(gmat + (size_t)(b0 + srow     ) * KW + gk);
        *(u16x8*)&At[srow + 64][soct * 8] = *(const u16x8*)(gmat + (size_t)(b0 + srow + 64) * KW + gk);
        *(u16x8*)&Bt[srow     ][soct * 8] = *(const u16x8*)(wmat + (size_t)(srow     ) * KW + gk);
        *(u16x8*)&Bt[srow + 64][soct * 8] = *(const u16x8*)(wmat + (size_t)(srow + 64) * KW + gk);
        __syncthreads();

        bf16x8 af[4], bfr[4];
        #pragma unroll
        for (int m = 0; m < 4; ++m) af[m]  = *(const bf16x8*)&At[wm + m * 16 + arow][aoct];
        #pragma unroll
        for (int n = 0; n < 4; ++n) bfr[n] = *(const bf16x8*)&Bt[wn + n * 16 + arow][aoct];
        #pragma unroll
        for (int m = 0; m < 4; ++m)
            #pragma unroll
            for (int n = 0; n < 4; ++n)
                acc[m][n] = __builtin_amdgcn_mfma_f32_16x16x32_bf16(af[m], bfr[n], acc[m][n], 0, 0, 0);
        __syncthreads();
    }

    float* pout = partial + (size_t)blockIdx.y * (NB * HID);
    #pragma unroll
    for (int m = 0; m < 4; ++m) {
        const int rbase = b0 + wm + m * 16 + (lane >> 4) * 4;
        #pragma unroll
        for (int n = 0; n < 4; ++n) {
            const int col = wn + n * 16 + (lane & 15);
            #pragma unroll
            for (int r = 0; r < 4; ++r)
                pout[(size_t)(rbase + r) * HID + col] = acc[m][n][r];
        }
    }
}

// ---------------------------------------------------------------------------
// R: reduce split-K partials + b1 + ReLU, then FC2 (128->2) + b2
// ---------------------------------------------------------------------------
__global__ __launch_bounds__(128) void reduce_fc2(
    const float* __restrict__ partial,  // [NKT][NB][HID]
    const float* __restrict__ b1,
    const float* __restrict__ w2,       // [NCLS][HID]
    const float* __restrict__ b2,
    float* __restrict__ out)            // [NB][NCLS]
{
    __shared__ float red0[128], red1[128];
    const int b = blockIdx.x, j = threadIdx.x;
    float s = b1[j];
    #pragma unroll 4
    for (int p = 0; p < NKT; ++p) s += partial[(size_t)p * (NB * HID) + b * HID + j];
    float h = fmaxf(s, 0.f);
    red0[j] = h * w2[j];
    red1[j] = h * w2[HID + j];
    __syncthreads();
    for (int off = 64; off > 0; off >>= 1) {
        if (j < off) { red0[j] += red0[j + off]; red1[j] += red1[j + off]; }
        __syncthreads();
    }
    if (j == 0) {
        out[b * 2 + 0] = red0[0] + b2[0];
        out[b * 2 + 1] = red1[0] + b2[1];
    }
}

// ---------------------------------------------------------------------------
extern "C" void kernel_launch(void* const* d_in, const int* in_sizes, int n_in,
                              void* d_out, int out_size, void* d_ws, size_t ws_size,
                              hipStream_t stream) {
    const float* x        = (const float*)d_in[0];
    const float* conv_w   = (const float*)d_in[1];
    const float* conv_b   = (const float*)d_in[2];
    const float* bn_gamma = (const float*)d_in[3];
    const float* bn_beta  = (const float*)d_in[4];
    const float* bn_mean  = (const float*)d_in[5];
    const float* bn_var   = (const float*)d_in[6];
    const float* adj      = (const float*)d_in[7];
    const float* gcn_w    = (const float*)d_in[8];
    const float* gcn_b    = (const float*)d_in[9];
    const float* w1       = (const float*)d_in[10];
    const float* b1       = (const float*)d_in[11];
    const float* w2       = (const float*)d_in[12];
    const float* b2       = (const float*)d_in[13];
    float* out = (float*)d_out;

    // workspace (H buffer eliminated by fusion):
    //   g2   [0,           83,886,080)   conv_mix -> gemm_fc1
    //   w1p  [83,886,080,  94,371,840)   w1_permute -> gemm
    //   part [94,371,840, 115,343,360)   gemm -> reduce
    //   m2g  [125,829,120, 125,931,520)  prep_m2 -> conv_mix
    //   A_g/bnS/bnB after that
    char* ws = (char*)d_ws;
    __bf16* g2   = (__bf16*)ws;
    __bf16* w1p  = (__bf16*)(ws + 83886080);
    float*  part = (float*)(ws + 94371840);
    __bf16* m2g  = (__bf16*)(ws + 125829120);
    float*  A_g  = (float*)(ws + 125931520);
    float*  bnS  = (float*)(ws + 125933568);
    float*  bnB  = (float*)(ws + 125934592);

    prep_small<<<dim3(1), dim3(256), 0, stream>>>(
        adj, bn_gamma, bn_beta, bn_mean, bn_var, conv_b, A_g, bnS, bnB);
    prep_m2<<<dim3(200), dim3(256), 0, stream>>>(A_g, gcn_w, m2g);
    conv_mix<<<dim3(NB), dim3(256), 0, stream>>>(x, conv_w, bnS, bnB, m2g, gcn_b, g2);
    w1_permute<<<dim3(HID * (KW / 8) / 256), dim3(256), 0, stream>>>(w1, w1p);
    gemm_fc1<<<dim3(8, NKT), dim3(256), 0, stream>>>(g2, w1p, part);
    reduce_fc2<<<dim3(NB), dim3(128), 0, stream>>>(part, b1, w2, b2, out);
}

// Round 11
// 113.905 us; speedup vs baseline: 1.1295x; 1.1295x over previous
//
#include <hip/hip_runtime.h>

// ---------------- problem constants ----------------
#define NB    1024
#define NN    19
#define NF    8
#define CCH   152         // NN*NF
#define TLEN  512
#define TP    128
#define GO    16
#define KFLAT 38912       // reference flat K (n*2048 + t*16 + o)
#define HID   128
#define NCLS  2
#define NROWS (NB*TP)     // 131072 (b,t) rows
#define KC    152         // conv channels (j,f)
#define KP    160         // padded K for mix (5*32)
#define NJP   20          // H j-planes (19 + zero pad)
#define NOUT  304         // NN*GO
#define GW    320         // g2 padded row width
#define KW    (TP*GW)     // 40960: FC1 K in permuted order

// FC1 GEMM split-K
#define KTILE 1024
#define NKT   (KW / KTILE)   // 40

typedef float  f32x4  __attribute__((ext_vector_type(4)));
typedef __bf16 bf16x8 __attribute__((ext_vector_type(8)));
typedef __bf16 bf16x4 __attribute__((ext_vector_type(4)));
typedef unsigned short u16x8 __attribute__((ext_vector_type(8)));

// ---------------------------------------------------------------------------
// P1: softmax(adj) + fused BN affine (1 block)
// ---------------------------------------------------------------------------
__global__ __launch_bounds__(256) void prep_small(
    const float* __restrict__ adj,
    const float* __restrict__ bn_gamma, const float* __restrict__ bn_beta,
    const float* __restrict__ bn_mean,  const float* __restrict__ bn_var,
    const float* __restrict__ conv_b,
    float* __restrict__ A_g, float* __restrict__ bnS, float* __restrict__ bnB)
{
    const int tid = threadIdx.x;
    if (tid < NN) {
        float v[NN];
        float m = -1e30f;
        #pragma unroll
        for (int j = 0; j < NN; ++j) { v[j] = adj[tid * NN + j]; m = fmaxf(m, v[j]); }
        float s = 0.f;
        #pragma unroll
        for (int j = 0; j < NN; ++j) { v[j] = expf(v[j] - m); s += v[j]; }
        float rc = 1.f / s;
        #pragma unroll
        for (int j = 0; j < NN; ++j) A_g[tid * NN + j] = v[j] * rc;
    }
    if (tid >= 64 && tid < 64 + CCH) {
        int c = tid - 64;
        float inv = bn_gamma[c] * rsqrtf(bn_var[c] + 1e-5f);
        bnS[c] = inv;
        bnB[c] = conv_b[c] * inv + bn_beta[c] - bn_mean[c] * inv;
    }
}

// ---------------------------------------------------------------------------
// P2: Kronecker matrix m2g[c][k] = A[n,j]*gcn_w[o,f], c=(n*16+o) in [0,320)
// ---------------------------------------------------------------------------
__global__ __launch_bounds__(256) void prep_m2(
    const float* __restrict__ A_g, const float* __restrict__ gcn_w,
    __bf16* __restrict__ m2g)
{
    int i = blockIdx.x * 256 + threadIdx.x;
    if (i >= GW * KP) return;
    int c = i / KP, k = i - c * KP;
    float v = 0.f;
    if (c < NOUT && k < KC) {
        int n = c >> 4, o = c & 15;
        int j = k >> 3, f = k & 7;
        v = A_g[n * NN + j] * gcn_w[o * NF + f];
    }
    m2g[i] = (__bf16)v;
}

// ---------------------------------------------------------------------------
// F: FUSED conv+bn+relu+pool + A-mix/gcn MFMA -> g2[(b,t)][320].
//    v2 (fixes R10's 1-block/CU occupancy collapse):
//    - grid 2048 = (batch, time-half): 64 pooled t per block
//    - NO x staging in LDS (direct global reads, R9-conv_pool-style)
//    - LDS = Hs only (20.5 KB) -> occupancy VGPR-limited (~3 blocks/CU)
//    Phase 1: wave w handles planes n = w, w+4, ... (wave-uniform weights).
//    Phase 2: R9's proven reg-resident-m2 loop (25 frags in VGPRs).
// ---------------------------------------------------------------------------
__global__ __launch_bounds__(256) void conv_mix(
    const float* __restrict__ x,       // [NB][NN][TLEN]
    const float* __restrict__ conv_w,  // [CCH][5]
    const float* __restrict__ bnS, const float* __restrict__ bnB,
    const __bf16* __restrict__ m2g,    // [GW][KP]
    const float* __restrict__ gcn_b,   // [GO]
    __bf16* __restrict__ g2)           // [NROWS][GW]
{
    __shared__ __align__(16) __bf16 Hs[NJP][64][8];   // 20,480 B

    const int tid  = threadIdx.x;
    const int lane = tid & 63, w = tid >> 6;
    const int b    = blockIdx.x >> 1;
    const int half = blockIdx.x & 1;
    const int tp0  = half * 64;            // pooled-t offset of this block

    // ---- phase 1: conv+bn+relu+pool -> Hs[n][t][f]; n = w+4k (wave-uniform)
    {
        const int t = lane;                        // local pooled t 0..63
        const int tg0 = 4 * (tp0 + t) - 2;         // global raw start
        for (int n = w; n < NN; n += 4) {
            const float* xr = x + ((size_t)b * NN + n) * TLEN;
            float xv[9];
            #pragma unroll
            for (int e = 0; e < 9; ++e) {
                int tg = tg0 + e;
                xv[e] = (tg >= 0 && tg < TLEN) ? xr[tg] : 0.f;
            }
            const float* cw = conv_w + n * (NF * 5);
            const float* Sp = bnS + n * NF;
            const float* Bp = bnB + n * NF;
            union { __bf16 h[8]; u16x8 v; } hv;
            #pragma unroll
            for (int f = 0; f < NF; ++f) {
                float w0 = cw[f*5+0], w1 = cw[f*5+1], w2 = cw[f*5+2], w3 = cw[f*5+3], w4 = cw[f*5+4];
                float s = Sp[f], bb = Bp[f];
                float m = -1e30f;
                #pragma unroll
                for (int p = 0; p < 4; ++p) {
                    float a = xv[p]*w0 + xv[p+1]*w1 + xv[p+2]*w2 + xv[p+3]*w3 + xv[p+4]*w4;
                    m = fmaxf(m, a * s + bb);
                }
                hv.h[f] = (__bf16)fmaxf(m, 0.f);
            }
            *(u16x8*)&Hs[n][t][0] = hv.v;
        }
        if (w == 3) {                              // zero plane 19 (K pad)
            u16x8 z = {0,0,0,0,0,0,0,0};
            *(u16x8*)&Hs[NJP - 1][lane][0] = z;
        }
    }

    // ---- m2 fragments from L2 (issued before barrier; latency hides) ----
    const int arow = lane & 15;
    const int jg   = lane >> 4;            // 0..3
    const int ct0  = w * 5;                // wave's 5 ct-tiles (80 cols)
    const float4 gbv = *(const float4*)(gcn_b + jg * 4);

    bf16x8 mf[5][5];
    #pragma unroll
    for (int ct = 0; ct < 5; ++ct)
        #pragma unroll
        for (int ks = 0; ks < 5; ++ks)
            mf[ct][ks] = *(const bf16x8*)(
                m2g + (size_t)((ct0 + ct) * 16 + arow) * KP + ks * 32 + jg * 8);

    __syncthreads();

    // ---- phase 2: 4 row-tiles x 25 MFMA, H frags from LDS ----
    for (int it = 0; it < 4; ++it) {
        const int tl = it * 16 + arow;     // local row 0..63

        bf16x8 af[5];
        #pragma unroll
        for (int ks = 0; ks < 5; ++ks)
            af[ks] = *(const bf16x8*)&Hs[ks * 4 + jg][tl][0];

        f32x4 acc[5];
        #pragma unroll
        for (int ct = 0; ct < 5; ++ct) acc[ct] = (f32x4){0.f, 0.f, 0.f, 0.f};

        #pragma unroll
        for (int ks = 0; ks < 5; ++ks)
            #pragma unroll
            for (int ct = 0; ct < 5; ++ct)
                acc[ct] = __builtin_amdgcn_mfma_f32_16x16x32_bf16(mf[ct][ks], af[ks], acc[ct], 0, 0, 0);

        // C^T: lane holds cols c = (ct0+ct)*16 + jg*4 + r, row b*128+tp0+tl
        __bf16* gp = g2 + ((size_t)b * TP + tp0 + tl) * GW + ct0 * 16 + jg * 4;
        #pragma unroll
        for (int ct = 0; ct < 5; ++ct) {
            bf16x4 v;
            v[0] = (__bf16)fmaxf(acc[ct][0] + gbv.x, 0.f);
            v[1] = (__bf16)fmaxf(acc[ct][1] + gbv.y, 0.f);
            v[2] = (__bf16)fmaxf(acc[ct][2] + gbv.z, 0.f);
            v[3] = (__bf16)fmaxf(acc[ct][3] + gbv.w, 0.f);
            *(bf16x4*)(gp + ct * 16) = v;
        }
    }
}

// ---------------------------------------------------------------------------
// W: permute+convert w1 -> w1p[j][t*320 + c] bf16 (c=(n*16+o); pad cols 0)
// ---------------------------------------------------------------------------
__global__ __launch_bounds__(256) void w1_permute(
    const float* __restrict__ w1, __bf16* __restrict__ w1p)
{
    int i = blockIdx.x * 256 + threadIdx.x;    // chunk: j*5120 + t*40 + c8
    if (i >= HID * (KW / 8)) return;
    int j = i / 5120, rem = i - j * 5120;
    int t = rem / 40, c8 = rem - t * 40;
    bf16x8 r;
    if (c8 < 38) {
        int n = c8 >> 1, o0 = (c8 & 1) * 8;
        const float* src = w1 + (size_t)j * KFLAT + n * 2048 + t * 16 + o0;
        #pragma unroll
        for (int e = 0; e < 8; ++e) r[e] = (__bf16)src[e];
    } else {
        #pragma unroll
        for (int e = 0; e < 8; ++e) r[e] = (__bf16)0.f;
    }
    *(bf16x8*)(w1p + (size_t)i * 8) = r;
}

// ---------------------------------------------------------------------------
// G: split-K bf16 MFMA GEMM: partial[kt][b][j] = sum_k g2[b][k]*w1p[j][k]
// ---------------------------------------------------------------------------
__global__ __launch_bounds__(256) void gemm_fc1(
    const __bf16* __restrict__ gmat,   // [NB][KW]
    const __bf16* __restrict__ wmat,   // [HID][KW]
    float* __restrict__ partial)       // [NKT][NB][HID]
{
    __shared__ __align__(16) __bf16 At[128][40];
    __shared__ __align__(16) __bf16 Bt[128][40];

    const int tid = threadIdx.x;
    const int b0 = blockIdx.x * 128;
    const int k0 = blockIdx.y * KTILE;

    const int lane = tid & 63;
    const int w = tid >> 6;
    const int wm = (w >> 1) * 64;
    const int wn = (w & 1) * 64;

    const int srow = tid >> 2;
    const int soct = tid & 3;

    f32x4 acc[4][4];
    #pragma unroll
    for (int m = 0; m < 4; ++m)
        #pragma unroll
        for (int n = 0; n < 4; ++n) acc[m][n] = (f32x4){0.f, 0.f, 0.f, 0.f};

    const int arow = lane & 15;
    const int aoct = (lane >> 4) * 8;

    for (int ks = 0; ks < KTILE / 32; ++ks) {
        const int gk = k0 + ks * 32 + soct * 8;
        *(u16x8*)&At[srow     ][soct * 8] = *(const u16x8*)(gmat + (size_t)(b0 + srow     ) * KW + gk);
        *(u16x8*)&At[srow + 64][soct * 8] = *(const u16x8*)(gmat + (size_t)(b0 + srow + 64) * KW + gk);
        *(u16x8*)&Bt[srow     ][soct * 8] = *(const u16x8*)(wmat + (size_t)(srow     ) * KW + gk);
        *(u16x8*)&Bt[srow + 64][soct * 8] = *(const u16x8*)(wmat + (size_t)(srow + 64) * KW + gk);
        __syncthreads();

        bf16x8 af[4], bfr[4];
        #pragma unroll
        for (int m = 0; m < 4; ++m) af[m]  = *(const bf16x8*)&At[wm + m * 16 + arow][aoct];
        #pragma unroll
        for (int n = 0; n < 4; ++n) bfr[n] = *(const bf16x8*)&Bt[wn + n * 16 + arow][aoct];
        #pragma unroll
        for (int m = 0; m < 4; ++m)
            #pragma unroll
            for (int n = 0; n < 4; ++n)
                acc[m][n] = __builtin_amdgcn_mfma_f32_16x16x32_bf16(af[m], bfr[n], acc[m][n], 0, 0, 0);
        __syncthreads();
    }

    float* pout = partial + (size_t)blockIdx.y * (NB * HID);
    #pragma unroll
    for (int m = 0; m < 4; ++m) {
        const int rbase = b0 + wm + m * 16 + (lane >> 4) * 4;
        #pragma unroll
        for (int n = 0; n < 4; ++n) {
            const int col = wn + n * 16 + (lane & 15);
            #pragma unroll
            for (int r = 0; r < 4; ++r)
                pout[(size_t)(rbase + r) * HID + col] = acc[m][n][r];
        }
    }
}

// ---------------------------------------------------------------------------
// R: reduce split-K partials + b1 + ReLU, then FC2 (128->2) + b2
// ---------------------------------------------------------------------------
__global__ __launch_bounds__(128) void reduce_fc2(
    const float* __restrict__ partial,  // [NKT][NB][HID]
    const float* __restrict__ b1,
    const float* __restrict__ w2,       // [NCLS][HID]
    const float* __restrict__ b2,
    float* __restrict__ out)            // [NB][NCLS]
{
    __shared__ float red0[128], red1[128];
    const int b = blockIdx.x, j = threadIdx.x;
    float s = b1[j];
    #pragma unroll 4
    for (int p = 0; p < NKT; ++p) s += partial[(size_t)p * (NB * HID) + b * HID + j];
    float h = fmaxf(s, 0.f);
    red0[j] = h * w2[j];
    red1[j] = h * w2[HID + j];
    __syncthreads();
    for (int off = 64; off > 0; off >>= 1) {
        if (j < off) { red0[j] += red0[j + off]; red1[j] += red1[j + off]; }
        __syncthreads();
    }
    if (j == 0) {
        out[b * 2 + 0] = red0[0] + b2[0];
        out[b * 2 + 1] = red1[0] + b2[1];
    }
}

// ---------------------------------------------------------------------------
extern "C" void kernel_launch(void* const* d_in, const int* in_sizes, int n_in,
                              void* d_out, int out_size, void* d_ws, size_t ws_size,
                              hipStream_t stream) {
    const float* x        = (const float*)d_in[0];
    const float* conv_w   = (const float*)d_in[1];
    const float* conv_b   = (const float*)d_in[2];
    const float* bn_gamma = (const float*)d_in[3];
    const float* bn_beta  = (const float*)d_in[4];
    const float* bn_mean  = (const float*)d_in[5];
    const float* bn_var   = (const float*)d_in[6];
    const float* adj      = (const float*)d_in[7];
    const float* gcn_w    = (const float*)d_in[8];
    const float* gcn_b    = (const float*)d_in[9];
    const float* w1       = (const float*)d_in[10];
    const float* b1       = (const float*)d_in[11];
    const float* w2       = (const float*)d_in[12];
    const float* b2       = (const float*)d_in[13];
    float* out = (float*)d_out;

    // workspace:
    //   g2   [0,           83,886,080)   conv_mix -> gemm_fc1
    //   w1p  [83,886,080,  94,371,840)   w1_permute -> gemm
    //   part [94,371,840, 115,343,360)   gemm -> reduce
    //   m2g  [125,829,120, 125,931,520)  prep_m2 -> conv_mix
    //   A_g/bnS/bnB after that
    char* ws = (char*)d_ws;
    __bf16* g2   = (__bf16*)ws;
    __bf16* w1p  = (__bf16*)(ws + 83886080);
    float*  part = (float*)(ws + 94371840);
    __bf16* m2g  = (__bf16*)(ws + 125829120);
    float*  A_g  = (float*)(ws + 125931520);
    float*  bnS  = (float*)(ws + 125933568);
    float*  bnB  = (float*)(ws + 125934592);

    prep_small<<<dim3(1), dim3(256), 0, stream>>>(
        adj, bn_gamma, bn_beta, bn_mean, bn_var, conv_b, A_g, bnS, bnB);
    prep_m2<<<dim3(200), dim3(256), 0, stream>>>(A_g, gcn_w, m2g);
    conv_mix<<<dim3(NB * 2), dim3(256), 0, stream>>>(x, conv_w, bnS, bnB, m2g, gcn_b, g2);
    w1_permute<<<dim3(HID * (KW / 8) / 256), dim3(256), 0, stream>>>(w1, w1p);
    gemm_fc1<<<dim3(8, NKT), dim3(256), 0, stream>>>(g2, w1p, part);
    reduce_fc2<<<dim3(NB), dim3(128), 0, stream>>>(part, b1, w2, b2, out);
}